// Round 11
// baseline (584.893 us; speedup 1.0000x reference)
//
#include <hip/hip_runtime.h>
#include <math.h>

#define N_ATOMS 50000
#define D 32
#define E_EDGES 300000
#define BD 16
#define SW 544                                // 17*32 (16 bond ch + 1 bias ch)
#define SCAN_BLOCKS ((N_ATOMS + 255) / 256)   // 196
#define GRU_TILE 8
#define GRU_NT (N_ATOMS / GRU_TILE)           // 6250

#define NB 64                                 // src nodes per block (8 per half-wave)
#define FBLOCKS ((N_ATOMS + NB - 1) / NB)     // 782

__device__ __forceinline__ float sigmoidf_(float x) {
    return 1.0f / (1.0f + __expf(-x));
}

// ---------- precompute (once per launch) ----------

// WTj[j*544 + b*32 + i] = W[b,i,j]  (b<16: kernel.reshape(16,32,32); b=16: Bm)
__global__ void k_build_wt(const float* __restrict__ kern,
                           const float* __restrict__ bias,
                           float* __restrict__ WTj) {
    int idx = blockIdx.x * 256 + threadIdx.x;
    if (idx >= 32 * SW) return;
    int j = idx / SW;
    int r = idx - j * SW;
    int b = r >> 5, i = r & 31;
    WTj[idx] = (b < BD) ? kern[b * 1024 + i * 32 + j] : bias[i * 32 + j];
}

// histogram over a column of pair (col=1: src, col=0: dst)
__global__ void k_hist(const int* __restrict__ pair, int* __restrict__ deg, int col) {
    int e = blockIdx.x * 256 + threadIdx.x;
    if (e < E_EDGES) atomicAdd(&deg[pair[2 * e + col]], 1);
}

__global__ void k_scan1(const int* __restrict__ deg, int* __restrict__ offs,
                        int* __restrict__ bsums) {
    __shared__ int sm[256];
    int t = threadIdx.x, gid = blockIdx.x * 256 + t;
    int v = (gid < N_ATOMS) ? deg[gid] : 0;
    sm[t] = v;
    __syncthreads();
    for (int off = 1; off < 256; off <<= 1) {
        int x = (t >= off) ? sm[t - off] : 0;
        __syncthreads();
        sm[t] += x;
        __syncthreads();
    }
    if (gid < N_ATOMS) offs[gid] = sm[t] - v;
    if (t == 255) bsums[blockIdx.x] = sm[255];
}

__global__ void k_scan2(const int* __restrict__ bsums, int* __restrict__ boffs, int nb) {
    __shared__ int sm[256];
    int t = threadIdx.x;
    int v = (t < nb) ? bsums[t] : 0;
    sm[t] = v;
    __syncthreads();
    for (int off = 1; off < 256; off <<= 1) {
        int x = (t >= off) ? sm[t - off] : 0;
        __syncthreads();
        sm[t] += x;
        __syncthreads();
    }
    if (t < nb) boffs[t] = sm[t] - v;
}

__global__ void k_scan3(int* __restrict__ offs, const int* __restrict__ boffs) {
    int gid = blockIdx.x * 256 + threadIdx.x;
    if (gid < N_ATOMS) offs[gid] += boffs[blockIdx.x];
}

// Permute edges to src-CSR order; materialize bond rows and dst in that order.
__global__ void k_scatter_perm(const int* __restrict__ pair, const int* __restrict__ offs,
                               int* __restrict__ cursor, const float* __restrict__ bond,
                               float* __restrict__ bond_perm, int* __restrict__ dstid) {
    int e = blockIdx.x * 256 + threadIdx.x;
    if (e >= E_EDGES) return;
    int d = pair[2 * e], s = pair[2 * e + 1];
    int pos = offs[s] + atomicAdd(&cursor[s], 1);
    dstid[pos] = d;
    const float4* src4 = (const float4*)(bond + (size_t)e * BD);
    float4* dst4 = (float4*)(bond_perm + (size_t)pos * BD);
    dst4[0] = src4[0];
    dst4[1] = src4[1];
    dst4[2] = src4[2];
    dst4[3] = src4[3];
}

// rpos[dst-CSR slot] = src-CSR position p  (gather map for k_aggru)
__global__ void k_rpos(const int* __restrict__ dstid, const int* __restrict__ offs2,
                       int* __restrict__ cursor2, int* __restrict__ rpos) {
    int p = blockIdx.x * 256 + threadIdx.x;
    if (p >= E_EDGES) return;
    int d = dstid[p];
    int slot = offs2[d] + atomicAdd(&cursor2[d], 1);
    rpos[slot] = p;
}

#define EDGE_FMA(M, B0, B1, B2, B3, YN) do {            \
    M = fmaf(B0.x, YN[0],  M); M = fmaf(B0.y, YN[1],  M); \
    M = fmaf(B0.z, YN[2],  M); M = fmaf(B0.w, YN[3],  M); \
    M = fmaf(B1.x, YN[4],  M); M = fmaf(B1.y, YN[5],  M); \
    M = fmaf(B1.z, YN[6],  M); M = fmaf(B1.w, YN[7],  M); \
    M = fmaf(B2.x, YN[8],  M); M = fmaf(B2.y, YN[9],  M); \
    M = fmaf(B2.z, YN[10], M); M = fmaf(B2.w, YN[11], M); \
    M = fmaf(B3.x, YN[12], M); M = fmaf(B3.y, YN[13], M); \
    M = fmaf(B3.z, YN[14], M); M = fmaf(B3.w, YN[15], M); \
} while (0)

// ---------- message kernel: projection in regs + SEQUENTIAL msg stores ----------
// Per half-wave: 8 src nodes. Phase A: y[n][b] in registers (lane = feature i).
// Phase B: walk outgoing edges in src-CSR order; msg row p is stored at
// msg_d[p*32+i] -- fully sequential, coalesced, write-combined. The dst
// randomness moves to k_aggru's READ side (gathers are ~16x faster per line
// than scattered writes on this chip: r7 57M lines/ms vs r9/r10 3.5M).
__global__ __launch_bounds__(256, 2)
void k_msg(const float* __restrict__ h_in, float* __restrict__ msg_d,
           const float* __restrict__ bond_perm, const float* __restrict__ WTj,
           const int* __restrict__ offs, const int* __restrict__ deg) {
    __shared__ float h_lds[NB][33];       // 8448 B

    const int t = threadIdx.x;
    const int bbase = blockIdx.x * NB;
    const int i = t & 31;                 // feature lane
    const int grp = t >> 5;               // half-wave 0..7
    const int hn0 = grp * 8;

#pragma unroll
    for (int k = 0; k < 8; ++k) {
        const int idx = t + 256 * k;      // 0..2047
        const int n = idx >> 5, j = idx & 31;
        const int node = bbase + n;
        h_lds[n][j] = (node < N_ATOMS) ? h_in[(size_t)node * D + j] : 0.f;
    }

    int stv[8], env[8];
#pragma unroll
    for (int n = 0; n < 8; ++n) {
        const int node = bbase + hn0 + n;
        const bool ok = (node < N_ATOMS);
        const int o = ok ? offs[node] : 0;
        stv[n] = o;
        env[n] = o + (ok ? deg[node] : 0);
    }
    __syncthreads();

    // Phase A: y[n][b] = sum_j WTj[j][b*32+i] * h[node_n][j]
    float y[8][17];
#pragma unroll
    for (int n = 0; n < 8; ++n)
#pragma unroll
        for (int b = 0; b < 17; ++b) y[n][b] = 0.f;

    for (int j = 0; j < 32; ++j) {        // not unrolled: keeps VGPR bounded
        float wv[17];
#pragma unroll
        for (int b = 0; b < 17; ++b)
            wv[b] = WTj[j * SW + b * 32 + i];   // coalesced, 8 nodes amortize
#pragma unroll
        for (int n = 0; n < 8; ++n) {
            const float hv = h_lds[hn0 + n][j]; // LDS broadcast
#pragma unroll
            for (int b = 0; b < 17; ++b)
                y[n][b] = fmaf(wv[b], hv, y[n][b]);
        }
    }

    // Phase B: linear bond stream in, SEQUENTIAL 128B rows out
#pragma unroll
    for (int n = 0; n < 8; ++n) {
        int p = stv[n];
        const int e = env[n];
        for (; p + 2 <= e; p += 2) {
            const float4* bp0 = (const float4*)(bond_perm + (size_t)p * BD);
            const float4* bp1 = (const float4*)(bond_perm + (size_t)(p + 1) * BD);
            const float4 a0 = bp0[0], a1 = bp0[1], a2 = bp0[2], a3 = bp0[3];
            const float4 c0 = bp1[0], c1 = bp1[1], c2 = bp1[2], c3 = bp1[3];
            float m0 = y[n][16];          // bias channel (bond == 1)
            float m1 = y[n][16];
            EDGE_FMA(m0, a0, a1, a2, a3, y[n]);
            EDGE_FMA(m1, c0, c1, c2, c3, y[n]);
            msg_d[(size_t)p * D + i] = m0;
            msg_d[(size_t)(p + 1) * D + i] = m1;
        }
        if (p < e) {
            const float4* bp0 = (const float4*)(bond_perm + (size_t)p * BD);
            const float4 a0 = bp0[0], a1 = bp0[1], a2 = bp0[2], a3 = bp0[3];
            float m0 = y[n][16];
            EDGE_FMA(m0, a0, a1, a2, a3, y[n]);
            msg_d[(size_t)p * D + i] = m0;
        }
    }
}

// ---------- aggregate (gather) + GRU fused ----------
// Per half-wave: one dst node per tile iteration. Messages gathered via
// rpos[] (random 128B line READS -- the fast direction), summed in regs,
// then GRU with weights in LDS.
__global__ __launch_bounds__(256, 2)
void k_aggru(const float* __restrict__ msg_d, const int* __restrict__ rpos,
             const int* __restrict__ offs2, const int* __restrict__ deg2,
             const float* __restrict__ h_in, float* __restrict__ h_out,
             const float* __restrict__ Wih, const float* __restrict__ Whh,
             const float* __restrict__ bih, const float* __restrict__ bhh) {
    __shared__ float Wih_s[96][33];
    __shared__ float Whh_s[96][33];
    __shared__ float bih_s[96], bhh_s[96];
    __shared__ float x_lds[GRU_TILE][32];
    __shared__ float h_lds[GRU_TILE][32];

    const int t = threadIdx.x;

    for (int idx = t; idx < 96 * 32; idx += 256) {
        const int o = idx >> 5, jj = idx & 31;
        Wih_s[o][jj] = Wih[idx];
        Whh_s[o][jj] = Whh[idx];
    }
    if (t < 96) { bih_s[t] = bih[t]; bhh_s[t] = bhh[t]; }

    const int r = t >> 5;   // node within octet / half-wave id
    const int i = t & 31;   // feature lane
    const int stride = gridDim.x;

    for (int tile = blockIdx.x; tile < GRU_NT; tile += stride) {
        const int node = tile * GRU_TILE + r;
        const int st = offs2[node];
        const int en = st + deg2[node];
        float acc = 0.f;
        int p = st;
        for (; p + 4 <= en; p += 4) {     // 4 gathered lines in flight
            const int p0 = rpos[p + 0];
            const int p1 = rpos[p + 1];
            const int p2 = rpos[p + 2];
            const int p3 = rpos[p + 3];
            const float a0 = msg_d[(size_t)p0 * D + i];
            const float a1 = msg_d[(size_t)p1 * D + i];
            const float a2 = msg_d[(size_t)p2 * D + i];
            const float a3 = msg_d[(size_t)p3 * D + i];
            acc += (a0 + a1) + (a2 + a3);
        }
        for (; p < en; ++p)
            acc += msg_d[(size_t)rpos[p] * D + i];
        x_lds[r][i] = acc;
        ((float*)h_lds)[t] = h_in[tile * 256 + t];
        __syncthreads();

        float gri = bih_s[i],      grh = bhh_s[i];
        float gzi = bih_s[32 + i], gzh = bhh_s[32 + i];
        float gni = bih_s[64 + i], gnh = bhh_s[64 + i];
#pragma unroll 8
        for (int jj = 0; jj < 32; ++jj) {
            const float xv = x_lds[r][jj];
            const float hv = h_lds[r][jj];
            gri = fmaf(Wih_s[i][jj],      xv, gri);
            gzi = fmaf(Wih_s[32 + i][jj], xv, gzi);
            gni = fmaf(Wih_s[64 + i][jj], xv, gni);
            grh = fmaf(Whh_s[i][jj],      hv, grh);
            gzh = fmaf(Whh_s[32 + i][jj], hv, gzh);
            gnh = fmaf(Whh_s[64 + i][jj], hv, gnh);
        }
        const float rg = sigmoidf_(gri + grh);
        const float zg = sigmoidf_(gzi + gzh);
        float xn = gni + rg * gnh;
        xn = fminf(fmaxf(xn, -15.f), 15.f);
        const float e2 = __expf(2.f * xn);
        const float ng = (e2 - 1.f) / (e2 + 1.f);
        h_out[tile * 256 + t] = (1.f - zg) * ng + zg * h_lds[r][i];
        __syncthreads();
    }
}

// ---------- launch ----------
extern "C" void kernel_launch(void* const* d_in, const int* in_sizes, int n_in,
                              void* d_out, int out_size, void* d_ws, size_t ws_size,
                              hipStream_t stream) {
    const float* atom = (const float*)d_in[0];
    const float* bond = (const float*)d_in[1];
    const int*   pair = (const int*)d_in[2];
    const float* kern = (const float*)d_in[3];
    const float* bias = (const float*)d_in[4];
    const float* Wih  = (const float*)d_in[5];
    const float* Whh  = (const float*)d_in[6];
    const float* bih  = (const float*)d_in[7];
    const float* bhh  = (const float*)d_in[8];
    float* out = (float*)d_out;

    char* w = (char*)d_ws;
    auto alloc = [&](size_t bytes) {
        char* p = w;
        w += (bytes + 255) & ~size_t(255);
        return p;
    };
    float* hA        = (float*)alloc((size_t)N_ATOMS * D * 4);
    float* WTj       = (float*)alloc((size_t)32 * SW * 4);
    int*   deg       = (int*)alloc((size_t)N_ATOMS * 4);
    int*   offs      = (int*)alloc((size_t)N_ATOMS * 4);
    int*   deg2      = (int*)alloc((size_t)N_ATOMS * 4);
    int*   offs2     = (int*)alloc((size_t)N_ATOMS * 4);
    int*   cursor    = (int*)alloc((size_t)N_ATOMS * 4);
    int*   cursor2   = (int*)alloc((size_t)N_ATOMS * 4);
    int*   bsums     = (int*)alloc(256 * 4);
    int*   boffs     = (int*)alloc(256 * 4);
    int*   dstid     = (int*)alloc((size_t)E_EDGES * 4);
    int*   rpos      = (int*)alloc((size_t)E_EDGES * 4);
    float* bond_perm = (float*)alloc((size_t)E_EDGES * BD * 4);
    float* msg_d     = (float*)alloc((size_t)E_EDGES * D * 4);   // 38.4 MB

    hipMemsetAsync(deg, 0, (size_t)N_ATOMS * 4, stream);
    hipMemsetAsync(deg2, 0, (size_t)N_ATOMS * 4, stream);
    hipMemsetAsync(cursor, 0, (size_t)N_ATOMS * 4, stream);
    hipMemsetAsync(cursor2, 0, (size_t)N_ATOMS * 4, stream);

    k_build_wt<<<(32 * SW + 255) / 256, 256, 0, stream>>>(kern, bias, WTj);
    // src-CSR
    k_hist<<<(E_EDGES + 255) / 256, 256, 0, stream>>>(pair, deg, 1);
    k_scan1<<<SCAN_BLOCKS, 256, 0, stream>>>(deg, offs, bsums);
    k_scan2<<<1, 256, 0, stream>>>(bsums, boffs, SCAN_BLOCKS);
    k_scan3<<<SCAN_BLOCKS, 256, 0, stream>>>(offs, boffs);
    // dst-CSR
    k_hist<<<(E_EDGES + 255) / 256, 256, 0, stream>>>(pair, deg2, 0);
    k_scan1<<<SCAN_BLOCKS, 256, 0, stream>>>(deg2, offs2, bsums);
    k_scan2<<<1, 256, 0, stream>>>(bsums, boffs, SCAN_BLOCKS);
    k_scan3<<<SCAN_BLOCKS, 256, 0, stream>>>(offs2, boffs);
    // permutations
    k_scatter_perm<<<(E_EDGES + 255) / 256, 256, 0, stream>>>(pair, offs, cursor,
                                                              bond, bond_perm, dstid);
    k_rpos<<<(E_EDGES + 255) / 256, 256, 0, stream>>>(dstid, offs2, cursor2, rpos);

    const float* hsrc = atom;
    float* hdst[4] = { hA, out, hA, out };
    for (int s = 0; s < 4; ++s) {
        k_msg<<<FBLOCKS, 256, 0, stream>>>(hsrc, msg_d, bond_perm, WTj, offs, deg);
        k_aggru<<<2048, 256, 0, stream>>>(msg_d, rpos, offs2, deg2, hsrc, hdst[s],
                                          Wih, Whh, bih, bhh);
        hsrc = hdst[s];
    }
}

// Round 12
// 560.256 us; speedup vs baseline: 1.0440x; 1.0440x over previous
//
#include <hip/hip_runtime.h>
#include <math.h>

#define N_ATOMS 50000
#define D 32
#define E_EDGES 300000
#define BD 16
#define SW 544                                // 17*32 (16 bond ch + 1 bias ch)
#define PADN 50176                            // 196*256
#define SCAN_BLOCKS 196
#define GRU_TILE 8
#define GRU_NT (N_ATOMS / GRU_TILE)           // 6250

#define NB 32                                 // src nodes per block (4 per half-wave)
#define FBLOCKS ((N_ATOMS + NB - 1) / NB)     // 1563

__device__ __forceinline__ float sigmoidf_(float x) {
    return 1.0f / (1.0f + __expf(-x));
}

// ---------- precompute (once per launch) ----------

// W2[j2*SW + b*32 + i] = {W[b,i,2*j2], W[b,i,2*j2+1]}  (b=16 -> Bm)
// Paired-j layout: Phase A loads one float2 per (j-pair, b) instead of two
// scalar b32 loads -> halves W-load instrs, enables v_pk_fma_f32 packing.
__global__ void k_build_wt2(const float* __restrict__ kern,
                            const float* __restrict__ bias,
                            float2* __restrict__ W2) {
    int idx = blockIdx.x * 256 + threadIdx.x;
    if (idx >= 16 * SW) return;
    int j2 = idx / SW;
    int r = idx - j2 * SW;
    int b = r >> 5, i = r & 31;
    const float* src = (b < BD) ? (kern + (size_t)b * 1024 + i * 32)
                                : (bias + (size_t)i * 32);
    W2[idx] = make_float2(src[2 * j2], src[2 * j2 + 1]);
}

// CSR by SRC (pair[:,1])
__global__ void k_hist(const int* __restrict__ pair, int* __restrict__ deg) {
    int e = blockIdx.x * 256 + threadIdx.x;
    if (e < E_EDGES) atomicAdd(&deg[pair[2 * e + 1]], 1);
}

__global__ void k_scan1(const int* __restrict__ deg, int* __restrict__ offs,
                        int* __restrict__ bsums) {
    __shared__ int sm[256];
    int t = threadIdx.x, gid = blockIdx.x * 256 + t;
    int v = deg[gid];                 // deg[50000..PADN) is zeroed
    sm[t] = v;
    __syncthreads();
    for (int off = 1; off < 256; off <<= 1) {
        int x = (t >= off) ? sm[t - off] : 0;
        __syncthreads();
        sm[t] += x;
        __syncthreads();
    }
    offs[gid] = sm[t] - v;
    if (t == 255) bsums[blockIdx.x] = sm[255];
}

__global__ void k_scan2(const int* __restrict__ bsums, int* __restrict__ boffs, int nb) {
    __shared__ int sm[256];
    int t = threadIdx.x;
    int v = (t < nb) ? bsums[t] : 0;
    sm[t] = v;
    __syncthreads();
    for (int off = 1; off < 256; off <<= 1) {
        int x = (t >= off) ? sm[t - off] : 0;
        __syncthreads();
        sm[t] += x;
        __syncthreads();
    }
    if (t < nb) boffs[t] = sm[t] - v;
}

__global__ void k_scan3(int* __restrict__ offs, const int* __restrict__ boffs) {
    int gid = blockIdx.x * 256 + threadIdx.x;
    offs[gid] += boffs[blockIdx.x];
}

// Permute edges to src-CSR order; materialize bond rows and dst in that order.
__global__ void k_scatter_perm(const int* __restrict__ pair, const int* __restrict__ offs,
                               int* __restrict__ cursor, const float* __restrict__ bond,
                               float* __restrict__ bond_perm, int* __restrict__ dstid) {
    int e = blockIdx.x * 256 + threadIdx.x;
    if (e >= E_EDGES) return;
    int d = pair[2 * e], s = pair[2 * e + 1];
    int pos = offs[s] + atomicAdd(&cursor[s], 1);
    dstid[pos] = d;
    const float4* src4 = (const float4*)(bond + (size_t)e * BD);
    float4* dst4 = (float4*)(bond_perm + (size_t)pos * BD);
    dst4[0] = src4[0];
    dst4[1] = src4[1];
    dst4[2] = src4[2];
    dst4[3] = src4[3];
}

#define EDGE_FMA(M, B0, B1, B2, B3, YN) do {            \
    M = fmaf(B0.x, YN[0],  M); M = fmaf(B0.y, YN[1],  M); \
    M = fmaf(B0.z, YN[2],  M); M = fmaf(B0.w, YN[3],  M); \
    M = fmaf(B1.x, YN[4],  M); M = fmaf(B1.y, YN[5],  M); \
    M = fmaf(B1.z, YN[6],  M); M = fmaf(B1.w, YN[7],  M); \
    M = fmaf(B2.x, YN[8],  M); M = fmaf(B2.y, YN[9],  M); \
    M = fmaf(B2.z, YN[10], M); M = fmaf(B2.w, YN[11], M); \
    M = fmaf(B3.x, YN[12], M); M = fmaf(B3.y, YN[13], M); \
    M = fmaf(B3.z, YN[14], M); M = fmaf(B3.w, YN[15], M); \
} while (0)

// ---------- fused projection + edge kernel (r9 structure, paired-j Phase A) ----------
// Per half-wave: 4 src nodes. Phase A: y[n][b] in registers (lane = feature i),
// j consumed in pairs via float2 W2/h2 (half the load+LDS instrs; fmaf pairs
// SLP-packable to v_pk_fma_f32). Phase B: linear bond_perm/dstid streams,
// one fire-and-forget 128B atomicAdd into agg[dst] per edge.
__global__ __launch_bounds__(256, 2)
void k_fused(const float* __restrict__ h_in, float* __restrict__ agg,
             const float* __restrict__ bond_perm, const int* __restrict__ dstid,
             const float2* __restrict__ W2,
             const int* __restrict__ offs, const int* __restrict__ deg) {
    __shared__ float2 h2[NB][17];         // 4352 B (17: +1 float2 row pad)

    const int t = threadIdx.x;
    const int bbase = blockIdx.x * NB;
    const int i = t & 31;                 // feature lane
    const int grp = t >> 5;               // half-wave 0..7
    const int hn0 = grp * 4;

    // ---- stage h tile as float2 pairs (coalesced, guarded)
#pragma unroll
    for (int k = 0; k < 2; ++k) {
        const int idx = t + 256 * k;      // 0..511 = 32 nodes x 16 float2
        const int n = idx >> 4, j2 = idx & 15;
        const int node = bbase + n;
        h2[n][j2] = (node < N_ATOMS) ? ((const float2*)h_in)[(size_t)node * 16 + j2]
                                     : make_float2(0.f, 0.f);
    }

    int stv[4], env[4];
#pragma unroll
    for (int n = 0; n < 4; ++n) {
        const int node = bbase + hn0 + n;
        const bool ok = (node < N_ATOMS);
        const int o = ok ? offs[node] : 0;
        stv[n] = o;
        env[n] = o + (ok ? deg[node] : 0);
    }
    __syncthreads();

    // ---- Phase A: y[n][b] = sum_j2 W2[j2][b*32+i] . h2[node_n][j2]
    float y[4][17];
#pragma unroll
    for (int n = 0; n < 4; ++n)
#pragma unroll
        for (int b = 0; b < 17; ++b) y[n][b] = 0.f;

    for (int j2 = 0; j2 < 16; ++j2) {     // not unrolled: bounds VGPR
        float2 wv[17];
#pragma unroll
        for (int b = 0; b < 17; ++b)
            wv[b] = W2[j2 * SW + b * 32 + i];   // 8B/lane, 256B/line-pair
#pragma unroll
        for (int n = 0; n < 4; ++n) {
            const float2 hv = h2[hn0 + n][j2];  // LDS broadcast (b64)
#pragma unroll
            for (int b = 0; b < 17; ++b)
                y[n][b] = fmaf(wv[b].y, hv.y, fmaf(wv[b].x, hv.x, y[n][b]));
        }
    }

    // ---- Phase B: linear streams in, fire-and-forget atomics out
#pragma unroll
    for (int n = 0; n < 4; ++n) {
        int p = stv[n];
        const int e = env[n];
        for (; p + 2 <= e; p += 2) {
            const float4* bp0 = (const float4*)(bond_perm + (size_t)p * BD);
            const float4* bp1 = (const float4*)(bond_perm + (size_t)(p + 1) * BD);
            const int d0 = dstid[p];
            const int d1 = dstid[p + 1];
            const float4 a0 = bp0[0], a1 = bp0[1], a2 = bp0[2], a3 = bp0[3];
            const float4 c0 = bp1[0], c1 = bp1[1], c2 = bp1[2], c3 = bp1[3];
            float m0 = y[n][16];          // bias channel (bond == 1)
            float m1 = y[n][16];
            EDGE_FMA(m0, a0, a1, a2, a3, y[n]);
            EDGE_FMA(m1, c0, c1, c2, c3, y[n]);
            atomicAdd(&agg[(size_t)d0 * D + i], m0);
            atomicAdd(&agg[(size_t)d1 * D + i], m1);
        }
        if (p < e) {
            const float4* bp0 = (const float4*)(bond_perm + (size_t)p * BD);
            const int d0 = dstid[p];
            const float4 a0 = bp0[0], a1 = bp0[1], a2 = bp0[2], a3 = bp0[3];
            float m0 = y[n][16];
            EDGE_FMA(m0, a0, a1, a2, a3, y[n]);
            atomicAdd(&agg[(size_t)d0 * D + i], m0);
        }
    }
}

// ---------- GRU kernel: h_out = GRUCell(agg, h_in); zeroes agg after read ----------
__global__ __launch_bounds__(256, 2)
void k_gru(float* __restrict__ agg_g, const float* __restrict__ h_in,
           float* __restrict__ h_out,
           const float* __restrict__ Wih, const float* __restrict__ Whh,
           const float* __restrict__ bih, const float* __restrict__ bhh) {
    __shared__ float Wih_s[96][33];
    __shared__ float Whh_s[96][33];
    __shared__ float bih_s[96], bhh_s[96];
    __shared__ float x_lds[GRU_TILE][32];
    __shared__ float h_lds[GRU_TILE][32];

    const int t = threadIdx.x;

    for (int idx = t; idx < 96 * 32; idx += 256) {
        const int o = idx >> 5, jj = idx & 31;
        Wih_s[o][jj] = Wih[idx];
        Whh_s[o][jj] = Whh[idx];
    }
    if (t < 96) { bih_s[t] = bih[t]; bhh_s[t] = bhh[t]; }

    const int r = t >> 5;
    const int i = t & 31;
    const int stride = gridDim.x;

    int tile = blockIdx.x;
    float xr = 0.f, hr = 0.f;
    if (tile < GRU_NT) {
        xr = agg_g[tile * 256 + t];
        hr = h_in[tile * 256 + t];
    }
    for (; tile < GRU_NT; tile += stride) {
        ((float*)x_lds)[t] = xr;
        ((float*)h_lds)[t] = hr;
        agg_g[tile * 256 + t] = 0.f;      // consumed -> zero for next step
        __syncthreads();
        const int nxt = tile + stride;
        if (nxt < GRU_NT) {               // prefetch next tile during compute
            xr = agg_g[nxt * 256 + t];
            hr = h_in[nxt * 256 + t];
        }
        float gri = bih_s[i],      grh = bhh_s[i];
        float gzi = bih_s[32 + i], gzh = bhh_s[32 + i];
        float gni = bih_s[64 + i], gnh = bhh_s[64 + i];
#pragma unroll 8
        for (int jj = 0; jj < 32; ++jj) {
            const float xv = x_lds[r][jj];
            const float hv = h_lds[r][jj];
            gri = fmaf(Wih_s[i][jj],      xv, gri);
            gzi = fmaf(Wih_s[32 + i][jj], xv, gzi);
            gni = fmaf(Wih_s[64 + i][jj], xv, gni);
            grh = fmaf(Whh_s[i][jj],      hv, grh);
            gzh = fmaf(Whh_s[32 + i][jj], hv, gzh);
            gnh = fmaf(Whh_s[64 + i][jj], hv, gnh);
        }
        const float rg = sigmoidf_(gri + grh);
        const float zg = sigmoidf_(gzi + gzh);
        float xn = gni + rg * gnh;
        xn = fminf(fmaxf(xn, -15.f), 15.f);
        const float e2 = __expf(2.f * xn);
        const float ng = (e2 - 1.f) / (e2 + 1.f);
        h_out[tile * 256 + t] = (1.f - zg) * ng + zg * h_lds[r][i];
        __syncthreads();
    }
}

// ---------- launch ----------
extern "C" void kernel_launch(void* const* d_in, const int* in_sizes, int n_in,
                              void* d_out, int out_size, void* d_ws, size_t ws_size,
                              hipStream_t stream) {
    const float* atom = (const float*)d_in[0];
    const float* bond = (const float*)d_in[1];
    const int*   pair = (const int*)d_in[2];
    const float* kern = (const float*)d_in[3];
    const float* bias = (const float*)d_in[4];
    const float* Wih  = (const float*)d_in[5];
    const float* Whh  = (const float*)d_in[6];
    const float* bih  = (const float*)d_in[7];
    const float* bhh  = (const float*)d_in[8];
    float* out = (float*)d_out;

    char* w = (char*)d_ws;
    auto alloc = [&](size_t bytes) {
        char* p = w;
        w += (bytes + 255) & ~size_t(255);
        return p;
    };
    float*  hA        = (float*)alloc((size_t)N_ATOMS * D * 4);
    float*  aggG      = (float*)alloc((size_t)N_ATOMS * D * 4);
    float2* W2        = (float2*)alloc((size_t)16 * SW * 8);
    int*    degcur    = (int*)alloc((size_t)2 * PADN * 4);   // deg | cursor
    int*    offs      = (int*)alloc((size_t)PADN * 4);
    int*    bsums     = (int*)alloc(256 * 4);
    int*    boffs     = (int*)alloc(256 * 4);
    int*    dstid     = (int*)alloc((size_t)E_EDGES * 4);
    float*  bond_perm = (float*)alloc((size_t)E_EDGES * BD * 4);
    int* deg    = degcur;
    int* cursor = degcur + PADN;

    hipMemsetAsync(degcur, 0, (size_t)2 * PADN * 4, stream);
    hipMemsetAsync(aggG, 0, (size_t)N_ATOMS * D * 4, stream);  // k_gru re-zeroes thereafter

    k_build_wt2<<<(16 * SW + 255) / 256, 256, 0, stream>>>(kern, bias, W2);
    k_hist<<<(E_EDGES + 255) / 256, 256, 0, stream>>>(pair, deg);
    k_scan1<<<SCAN_BLOCKS, 256, 0, stream>>>(deg, offs, bsums);
    k_scan2<<<1, 256, 0, stream>>>(bsums, boffs, SCAN_BLOCKS);
    k_scan3<<<SCAN_BLOCKS, 256, 0, stream>>>(offs, boffs);
    k_scatter_perm<<<(E_EDGES + 255) / 256, 256, 0, stream>>>(pair, offs, cursor,
                                                              bond, bond_perm, dstid);

    const float* hsrc = atom;
    float* hdst[4] = { hA, out, hA, out };
    for (int s = 0; s < 4; ++s) {
        k_fused<<<FBLOCKS, 256, 0, stream>>>(hsrc, aggG, bond_perm, dstid,
                                             W2, offs, deg);
        k_gru<<<2048, 256, 0, stream>>>(aggG, hsrc, hdst[s], Wih, Whh, bih, bhh);
        hsrc = hdst[s];
    }
}

// Round 14
// 526.050 us; speedup vs baseline: 1.1119x; 1.0650x over previous
//
#include <hip/hip_runtime.h>
#include <math.h>

#define N_ATOMS 50000
#define D 32
#define E_EDGES 300000
#define BD 16
#define SW 544                                // 17*32 (16 bond ch + 1 bias ch)
#define PADN 50176                            // 196*256
#define SCAN_BLOCKS 196
#define GRU_TILE 8
#define GRU_NT (N_ATOMS / GRU_TILE)           // 6250

#define NB 16                                 // src nodes per block (2 per half-wave)
#define FBLOCKS ((N_ATOMS + NB - 1) / NB)     // 3125

__device__ __forceinline__ float sigmoidf_(float x) {
    return 1.0f / (1.0f + __expf(-x));
}

// ---------- precompute (once per launch) ----------

// WTj[j*544 + b*32 + i] = W[b,i,j]  (b<16: kernel.reshape(16,32,32); b=16: Bm)
__global__ void k_build_wt(const float* __restrict__ kern,
                           const float* __restrict__ bias,
                           float* __restrict__ WTj) {
    int idx = blockIdx.x * 256 + threadIdx.x;
    if (idx >= 32 * SW) return;
    int j = idx / SW;
    int r = idx - j * SW;
    int b = r >> 5, i = r & 31;
    WTj[idx] = (b < BD) ? kern[b * 1024 + i * 32 + j] : bias[i * 32 + j];
}

// CSR by SRC (pair[:,1])
__global__ void k_hist(const int* __restrict__ pair, int* __restrict__ deg) {
    int e = blockIdx.x * 256 + threadIdx.x;
    if (e < E_EDGES) atomicAdd(&deg[pair[2 * e + 1]], 1);
}

__global__ void k_scan1(const int* __restrict__ deg, int* __restrict__ offs,
                        int* __restrict__ bsums) {
    __shared__ int sm[256];
    int t = threadIdx.x, gid = blockIdx.x * 256 + t;
    int v = deg[gid];                 // deg[50000..PADN) is zeroed
    sm[t] = v;
    __syncthreads();
    for (int off = 1; off < 256; off <<= 1) {
        int x = (t >= off) ? sm[t - off] : 0;
        __syncthreads();
        sm[t] += x;
        __syncthreads();
    }
    offs[gid] = sm[t] - v;
    if (t == 255) bsums[blockIdx.x] = sm[255];
}

__global__ void k_scan2(const int* __restrict__ bsums, int* __restrict__ boffs, int nb) {
    __shared__ int sm[256];
    int t = threadIdx.x;
    int v = (t < nb) ? bsums[t] : 0;
    sm[t] = v;
    __syncthreads();
    for (int off = 1; off < 256; off <<= 1) {
        int x = (t >= off) ? sm[t - off] : 0;
        __syncthreads();
        sm[t] += x;
        __syncthreads();
    }
    if (t < nb) boffs[t] = sm[t] - v;
}

__global__ void k_scan3(int* __restrict__ offs, const int* __restrict__ boffs) {
    int gid = blockIdx.x * 256 + threadIdx.x;
    offs[gid] += boffs[blockIdx.x];
}

// Permute edges to src-CSR order; materialize bond rows and dst in that order.
__global__ void k_scatter_perm(const int* __restrict__ pair, const int* __restrict__ offs,
                               int* __restrict__ cursor, const float* __restrict__ bond,
                               float* __restrict__ bond_perm, int* __restrict__ dstid) {
    int e = blockIdx.x * 256 + threadIdx.x;
    if (e >= E_EDGES) return;
    int d = pair[2 * e], s = pair[2 * e + 1];
    int pos = offs[s] + atomicAdd(&cursor[s], 1);
    dstid[pos] = d;
    const float4* src4 = (const float4*)(bond + (size_t)e * BD);
    float4* dst4 = (float4*)(bond_perm + (size_t)pos * BD);
    dst4[0] = src4[0];
    dst4[1] = src4[1];
    dst4[2] = src4[2];
    dst4[3] = src4[3];
}

#define EDGE_FMA(M, B0, B1, B2, B3, YN) do {            \
    M = fmaf(B0.x, YN[0],  M); M = fmaf(B0.y, YN[1],  M); \
    M = fmaf(B0.z, YN[2],  M); M = fmaf(B0.w, YN[3],  M); \
    M = fmaf(B1.x, YN[4],  M); M = fmaf(B1.y, YN[5],  M); \
    M = fmaf(B1.z, YN[6],  M); M = fmaf(B1.w, YN[7],  M); \
    M = fmaf(B2.x, YN[8],  M); M = fmaf(B2.y, YN[9],  M); \
    M = fmaf(B2.z, YN[10], M); M = fmaf(B2.w, YN[11], M); \
    M = fmaf(B3.x, YN[12], M); M = fmaf(B3.y, YN[13], M); \
    M = fmaf(B3.z, YN[14], M); M = fmaf(B3.w, YN[15], M); \
} while (0)

// ---------- fused projection + edge kernel (r9 structure, NB=16, occ-tuned) ----------
// Per half-wave: 2 src nodes -> y[2][17] = 34 acc regs; peak live ~60 VGPR.
// __launch_bounds__(256,4) pushes the allocator under the 64-VGPR occupancy
// step (<=64 -> 8 waves/SIMD cap vs 4 at 65+). All prior evidence says the
// kernel is latency-bound (r9 atomics == r10 scatter == r11 sequential stores
// at occ 14-23%); more resident waves is the remaining lever.
__global__ __launch_bounds__(256, 4)
void k_fused(const float* __restrict__ h_in, float* __restrict__ agg,
             const float* __restrict__ bond_perm, const int* __restrict__ dstid,
             const float* __restrict__ WTj,
             const int* __restrict__ offs, const int* __restrict__ deg) {
    __shared__ float h_lds[NB][33];       // 2112 B

    const int t = threadIdx.x;
    const int bbase = blockIdx.x * NB;    // NB=16 divides 50000 -> no guards
    const int i = t & 31;                 // feature lane
    const int grp = t >> 5;               // half-wave 0..7
    const int hn0 = grp * 2;

    // ---- stage h tile (coalesced)
    {
        const int n = t >> 5;
        h_lds[n][i]     = h_in[(size_t)(bbase + n) * D + i];
        h_lds[n + 8][i] = h_in[(size_t)(bbase + n + 8) * D + i];
    }

    int stv[2], env[2];
#pragma unroll
    for (int n = 0; n < 2; ++n) {
        const int node = bbase + hn0 + n;
        const int o = offs[node];
        stv[n] = o;
        env[n] = o + deg[node];
    }
    __syncthreads();

    // ---- Phase A: y[n][b] = sum_j WTj[j][b*32+i] * h[node_n][j]
    float y[2][17];
#pragma unroll
    for (int n = 0; n < 2; ++n)
#pragma unroll
        for (int b = 0; b < 17; ++b) y[n][b] = 0.f;

    for (int j = 0; j < 32; ++j) {        // not unrolled: keeps VGPR <= 64
        float wv[17];
#pragma unroll
        for (int b = 0; b < 17; ++b)
            wv[b] = WTj[j * SW + b * 32 + i];
        const float hv0 = h_lds[hn0][j];
        const float hv1 = h_lds[hn0 + 1][j];
#pragma unroll
        for (int b = 0; b < 17; ++b) {
            y[0][b] = fmaf(wv[b], hv0, y[0][b]);
            y[1][b] = fmaf(wv[b], hv1, y[1][b]);
        }
    }

    // ---- Phase B: linear streams in, fire-and-forget atomics out
#pragma unroll
    for (int n = 0; n < 2; ++n) {
        int p = stv[n];
        const int e = env[n];
        for (; p + 2 <= e; p += 2) {
            const float4* bp0 = (const float4*)(bond_perm + (size_t)p * BD);
            const float4* bp1 = (const float4*)(bond_perm + (size_t)(p + 1) * BD);
            const int d0 = dstid[p];
            const int d1 = dstid[p + 1];
            const float4 a0 = bp0[0], a1 = bp0[1], a2 = bp0[2], a3 = bp0[3];
            const float4 c0 = bp1[0], c1 = bp1[1], c2 = bp1[2], c3 = bp1[3];
            float m0 = y[n][16];          // bias channel (bond == 1)
            float m1 = y[n][16];
            EDGE_FMA(m0, a0, a1, a2, a3, y[n]);
            EDGE_FMA(m1, c0, c1, c2, c3, y[n]);
            atomicAdd(&agg[(size_t)d0 * D + i], m0);
            atomicAdd(&agg[(size_t)d1 * D + i], m1);
        }
        if (p < e) {
            const float4* bp0 = (const float4*)(bond_perm + (size_t)p * BD);
            const int d0 = dstid[p];
            const float4 a0 = bp0[0], a1 = bp0[1], a2 = bp0[2], a3 = bp0[3];
            float m0 = y[n][16];
            EDGE_FMA(m0, a0, a1, a2, a3, y[n]);
            atomicAdd(&agg[(size_t)d0 * D + i], m0);
        }
    }
}

// ---------- GRU kernel: h_out = GRUCell(agg, h_in); zeroes agg after read ----------
__global__ __launch_bounds__(256, 2)
void k_gru(float* __restrict__ agg_g, const float* __restrict__ h_in,
           float* __restrict__ h_out,
           const float* __restrict__ Wih, const float* __restrict__ Whh,
           const float* __restrict__ bih, const float* __restrict__ bhh) {
    __shared__ float Wih_s[96][33];
    __shared__ float Whh_s[96][33];
    __shared__ float bih_s[96], bhh_s[96];
    __shared__ float x_lds[GRU_TILE][32];
    __shared__ float h_lds[GRU_TILE][32];

    const int t = threadIdx.x;

    for (int idx = t; idx < 96 * 32; idx += 256) {
        const int o = idx >> 5, jj = idx & 31;
        Wih_s[o][jj] = Wih[idx];
        Whh_s[o][jj] = Whh[idx];
    }
    if (t < 96) { bih_s[t] = bih[t]; bhh_s[t] = bhh[t]; }

    const int r = t >> 5;
    const int i = t & 31;
    const int stride = gridDim.x;

    int tile = blockIdx.x;
    float xr = 0.f, hr = 0.f;
    if (tile < GRU_NT) {
        xr = agg_g[tile * 256 + t];
        hr = h_in[tile * 256 + t];
    }
    for (; tile < GRU_NT; tile += stride) {
        ((float*)x_lds)[t] = xr;
        ((float*)h_lds)[t] = hr;
        agg_g[tile * 256 + t] = 0.f;      // consumed -> zero for next step
        __syncthreads();
        const int nxt = tile + stride;
        if (nxt < GRU_NT) {               // prefetch next tile during compute
            xr = agg_g[nxt * 256 + t];
            hr = h_in[nxt * 256 + t];
        }
        float gri = bih_s[i],      grh = bhh_s[i];
        float gzi = bih_s[32 + i], gzh = bhh_s[32 + i];
        float gni = bih_s[64 + i], gnh = bhh_s[64 + i];
#pragma unroll 8
        for (int jj = 0; jj < 32; ++jj) {
            const float xv = x_lds[r][jj];
            const float hv = h_lds[r][jj];
            gri = fmaf(Wih_s[i][jj],      xv, gri);
            gzi = fmaf(Wih_s[32 + i][jj], xv, gzi);
            gni = fmaf(Wih_s[64 + i][jj], xv, gni);
            grh = fmaf(Whh_s[i][jj],      hv, grh);
            gzh = fmaf(Whh_s[32 + i][jj], hv, gzh);
            gnh = fmaf(Whh_s[64 + i][jj], hv, gnh);
        }
        const float rg = sigmoidf_(gri + grh);
        const float zg = sigmoidf_(gzi + gzh);
        float xn = gni + rg * gnh;
        xn = fminf(fmaxf(xn, -15.f), 15.f);
        const float e2 = __expf(2.f * xn);
        const float ng = (e2 - 1.f) / (e2 + 1.f);
        h_out[tile * 256 + t] = (1.f - zg) * ng + zg * h_lds[r][i];
        __syncthreads();
    }
}

// ---------- launch ----------
extern "C" void kernel_launch(void* const* d_in, const int* in_sizes, int n_in,
                              void* d_out, int out_size, void* d_ws, size_t ws_size,
                              hipStream_t stream) {
    const float* atom = (const float*)d_in[0];
    const float* bond = (const float*)d_in[1];
    const int*   pair = (const int*)d_in[2];
    const float* kern = (const float*)d_in[3];
    const float* bias = (const float*)d_in[4];
    const float* Wih  = (const float*)d_in[5];
    const float* Whh  = (const float*)d_in[6];
    const float* bih  = (const float*)d_in[7];
    const float* bhh  = (const float*)d_in[8];
    float* out = (float*)d_out;

    char* w = (char*)d_ws;
    auto alloc = [&](size_t bytes) {
        char* p = w;
        w += (bytes + 255) & ~size_t(255);
        return p;
    };
    float* hA        = (float*)alloc((size_t)N_ATOMS * D * 4);
    float* aggG      = (float*)alloc((size_t)N_ATOMS * D * 4);
    float* WTj       = (float*)alloc((size_t)32 * SW * 4);
    int*   degcur    = (int*)alloc((size_t)2 * PADN * 4);   // deg | cursor
    int*   offs      = (int*)alloc((size_t)PADN * 4);
    int*   bsums     = (int*)alloc(256 * 4);
    int*   boffs     = (int*)alloc(256 * 4);
    int*   dstid     = (int*)alloc((size_t)E_EDGES * 4);
    float* bond_perm = (float*)alloc((size_t)E_EDGES * BD * 4);
    int* deg    = degcur;
    int* cursor = degcur + PADN;

    hipMemsetAsync(degcur, 0, (size_t)2 * PADN * 4, stream);
    hipMemsetAsync(aggG, 0, (size_t)N_ATOMS * D * 4, stream);  // k_gru re-zeroes thereafter

    k_build_wt<<<(32 * SW + 255) / 256, 256, 0, stream>>>(kern, bias, WTj);
    k_hist<<<(E_EDGES + 255) / 256, 256, 0, stream>>>(pair, deg);
    k_scan1<<<SCAN_BLOCKS, 256, 0, stream>>>(deg, offs, bsums);
    k_scan2<<<1, 256, 0, stream>>>(bsums, boffs, SCAN_BLOCKS);
    k_scan3<<<SCAN_BLOCKS, 256, 0, stream>>>(offs, boffs);
    k_scatter_perm<<<(E_EDGES + 255) / 256, 256, 0, stream>>>(pair, offs, cursor,
                                                              bond, bond_perm, dstid);

    const float* hsrc = atom;
    float* hdst[4] = { hA, out, hA, out };
    for (int s = 0; s < 4; ++s) {
        k_fused<<<FBLOCKS, 256, 0, stream>>>(hsrc, aggG, bond_perm, dstid,
                                             WTj, offs, deg);
        k_gru<<<2048, 256, 0, stream>>>(aggG, hsrc, hdst[s], Wih, Whh, bih, bhh);
        hsrc = hdst[s];
    }
}